// Round 2
// baseline (1134.228 us; speedup 1.0000x reference)
//
#include <hip/hip_runtime.h>
#include <hip/hip_bf16.h>

typedef __attribute__((ext_vector_type(8))) short short8;
typedef __attribute__((ext_vector_type(4))) float floatx4;

#define D_DIM 256
#define K_DIM 768
#define TILE 128

// fp32 -> bf16 round-to-nearest-even
__device__ __forceinline__ short f2bf(float x) {
    union { float f; unsigned u; } a; a.f = x;
    unsigned r = a.u + 0x7fffu + ((a.u >> 16) & 1u);
    return (short)(r >> 16);
}

// W [K_DIM][D_DIM] fp32 -> Wt [D_DIM][K_DIM] bf16 (transpose + convert)
__global__ __launch_bounds__(256) void wt_kernel(const float* __restrict__ W,
                                                 short* __restrict__ Wt) {
    __shared__ float tile[32][33];
    const int k0 = blockIdx.x * 32, n0 = blockIdx.y * 32;
    const int tx = threadIdx.x & 31, ty = threadIdx.x >> 5;
#pragma unroll
    for (int i = 0; i < 32; i += 8)
        tile[ty + i][tx] = W[(size_t)(k0 + ty + i) * D_DIM + n0 + tx];
    __syncthreads();
#pragma unroll
    for (int i = 0; i < 32; i += 8)
        Wt[(size_t)(n0 + ty + i) * K_DIM + k0 + tx] = f2bf(tile[tx][ty + i]);
}

// Barrier-free fused gather+GEMM: every lane loads its MFMA fragments
// directly from global memory (A: fp32 rows via gather + cvt; B: bf16 Wt
// rows resident in L2). No LDS, no __syncthreads in the K-loop -> compiler
// software-pipelines loads across the fully unrolled 24 K-iterations.
__global__ __launch_bounds__(256) void edge_gemm(
    const float* __restrict__ edge, const float* __restrict__ node,
    const int* __restrict__ src, const int* __restrict__ tgt,
    const short* __restrict__ Wt, const float* __restrict__ bias,
    float* __restrict__ out, int E)
{
    const int tid  = threadIdx.x;
    const int lane = tid & 63;
    const int wave = tid >> 6;            // 0..3
    const int wm   = (wave >> 1) * 64;    // wave m-offset within 128-tile
    const int wn   = (wave & 1) * 64;     // wave n-offset within 128-tile
    const int fr   = lane & 15;           // fragment row/col index
    const int kq   = (lane >> 4) * 8;     // k-quad offset within 32-chunk

    const int m0 = blockIdx.y * TILE;
    const int n0 = blockIdx.x * TILE;

    // Per-lane A base pointers: [segment][m-fragment]
    const float* aptr[3][4];
#pragma unroll
    for (int i = 0; i < 4; ++i) {
        int r = m0 + wm + i * 16 + fr;
        int rc = r < E ? r : E - 1;       // clamp (stores guarded below)
        int s = src[rc], t = tgt[rc];
        aptr[0][i] = edge + (size_t)rc * D_DIM + kq;
        aptr[1][i] = node + (size_t)s  * D_DIM + kq;
        aptr[2][i] = node + (size_t)t  * D_DIM + kq;
    }
    const short* bptr[4];
#pragma unroll
    for (int j = 0; j < 4; ++j)
        bptr[j] = Wt + (size_t)(n0 + wn + j * 16 + fr) * K_DIM + kq;

    floatx4 acc[4][4] = {};

#pragma unroll
    for (int seg = 0; seg < 3; ++seg) {
#pragma unroll
        for (int it = 0; it < 8; ++it) {
            short8 bfr[4];
#pragma unroll
            for (int j = 0; j < 4; ++j)
                bfr[j] = *(const short8*)(bptr[j] + seg * D_DIM + it * 32);

            short8 afr[4];
#pragma unroll
            for (int i = 0; i < 4; ++i) {
                const float4* p = (const float4*)(aptr[seg][i] + it * 32);
                float4 f0 = p[0], f1 = p[1];
                union { short8 v; short s[8]; } u;
                u.s[0] = f2bf(f0.x); u.s[1] = f2bf(f0.y);
                u.s[2] = f2bf(f0.z); u.s[3] = f2bf(f0.w);
                u.s[4] = f2bf(f1.x); u.s[5] = f2bf(f1.y);
                u.s[6] = f2bf(f1.z); u.s[7] = f2bf(f1.w);
                afr[i] = u.v;
            }
#pragma unroll
            for (int i = 0; i < 4; ++i)
#pragma unroll
                for (int j = 0; j < 4; ++j)
                    acc[i][j] = __builtin_amdgcn_mfma_f32_16x16x32_bf16(
                        afr[i], bfr[j], acc[i][j], 0, 0, 0);
        }
    }

    // Epilogue: bias + relu + guarded store.
    // C/D layout: col = lane&15, row = (lane>>4)*4 + reg.
    float bv[4];
#pragma unroll
    for (int j = 0; j < 4; ++j) bv[j] = bias[n0 + wn + j * 16 + fr];
    const int rq = (lane >> 4) * 4;
#pragma unroll
    for (int i = 0; i < 4; ++i) {
        const int rbase = m0 + wm + i * 16 + rq;
#pragma unroll
        for (int j = 0; j < 4; ++j) {
            const int c = n0 + wn + j * 16 + fr;
#pragma unroll
            for (int r = 0; r < 4; ++r) {
                const int rr = rbase + r;
                if (rr < E) {
                    float v = acc[i][j][r] + bv[j];
                    out[(size_t)rr * D_DIM + c] = v > 0.f ? v : 0.f;
                }
            }
        }
    }
}

extern "C" void kernel_launch(void* const* d_in, const int* in_sizes, int n_in,
                              void* d_out, int out_size, void* d_ws, size_t ws_size,
                              hipStream_t stream) {
    const float* edge = (const float*)d_in[0];
    const float* node = (const float*)d_in[1];
    const int*   srcI = (const int*)d_in[2];
    const int*   tgtI = (const int*)d_in[3];
    const float* W    = (const float*)d_in[4];
    const float* bias = (const float*)d_in[5];
    float* out = (float*)d_out;
    const int E = in_sizes[2];
    short* Wt = (short*)d_ws;  // K_DIM*D_DIM*2 = 393216 B

    dim3 tgrid(K_DIM / 32, D_DIM / 32);
    wt_kernel<<<tgrid, dim3(256), 0, stream>>>(W, Wt);

    dim3 ggrid(D_DIM / TILE, (E + TILE - 1) / TILE);  // N fastest: A reuse via L2/L3
    edge_gemm<<<ggrid, dim3(256), 0, stream>>>(edge, node, srcI, tgtI, Wt, bias, out, E);
}